// Round 7
// baseline (588.794 us; speedup 1.0000x reference)
//
#include <hip/hip_runtime.h>
#include <math.h>

#define NN 768
#define CS 384
#define CZ 128
#define CH 16
#define HH 12
#define PQ 4
#define PV 8
#define OUTIN 2112

#define SC_QK 0.14433756729740643f   // sqrt(1/(3*16))
#define SC_B  0.57735026918962576f   // sqrt(1/3)
#define SC_HW 0.13608276348795434f   // sqrt(2/(27*4))

// ---------------- Kernel A: input projections (s @ W.T + b) ----------------
__global__ __launch_bounds__(256) void kproj(
    const float* __restrict__ s,
    const float* __restrict__ Wq,  const float* __restrict__ bq,
    const float* __restrict__ Wkv, const float* __restrict__ bkv,
    const float* __restrict__ Wqp, const float* __restrict__ bqp,
    const float* __restrict__ Wkvp,const float* __restrict__ bkvp,
    float* __restrict__ q, float* __restrict__ kT, float* __restrict__ vallT,
    float* __restrict__ qpr, float* __restrict__ kvpr)
{
    __shared__ float s_lds[8*384];
    int n0 = blockIdx.x * 8;
    int t = threadIdx.x;
    for (int idx = t; idx < 8*384; idx += 256)
        s_lds[idx] = s[(n0 + idx/384)*384 + (idx%384)];
    __syncthreads();

    int o = blockIdx.y * 128 + (t & 127);
    int ng = t >> 7;
    const float* wrow; float bias;
    if (o < 192)      { wrow = Wq   + o*384;       bias = bq[o]; }
    else if (o < 576) { wrow = Wkv  + (o-192)*384; bias = bkv[o-192]; }
    else if (o < 720) { wrow = Wqp  + (o-576)*384; bias = bqp[o-576]; }
    else              { wrow = Wkvp + (o-720)*384; bias = bkvp[o-720]; }

    float acc[4] = {bias, bias, bias, bias};
    const float4* wr4 = reinterpret_cast<const float4*>(wrow);
    for (int c4 = 0; c4 < 96; ++c4) {
        float4 w = wr4[c4];
        #pragma unroll
        for (int nn = 0; nn < 4; ++nn) {
            const float* sr = &s_lds[(ng*4+nn)*384 + c4*4];
            acc[nn] = fmaf(w.x, sr[0], acc[nn]);
            acc[nn] = fmaf(w.y, sr[1], acc[nn]);
            acc[nn] = fmaf(w.z, sr[2], acc[nn]);
            acc[nn] = fmaf(w.w, sr[3], acc[nn]);
        }
    }
    #pragma unroll
    for (int nn = 0; nn < 4; ++nn) {
        int n = n0 + ng*4 + nn;
        float v = acc[nn];
        if (o < 192)      q[n*192 + o] = v;
        else if (o < 576) {
            int oo = o - 192, h = oo >> 5, cc = oo & 31;
            if (cc < 16) kT[(h*NN + n)*16 + cc] = v;
            else         vallT[(size_t)(h*40 + (cc-16))*NN + n] = v;
        }
        else if (o < 720) qpr[n*144 + (o-576)] = v;
        else              kvpr[n*432 + (o-720)] = v;
    }
}

// ---------------- Kernel B: apply frames (rot, trans) to points ----------------
__global__ __launch_bounds__(192) void krot(
    const float* __restrict__ rot, const float* __restrict__ trans,
    const float* __restrict__ qpr, const float* __restrict__ kvpr,
    float* __restrict__ qp, float* __restrict__ kpT, float* __restrict__ vallT)
{
    int n = blockIdx.x;
    __shared__ float R[9], T[3];
    int t = threadIdx.x;
    if (t < 9) R[t] = rot[n*9 + t];
    if (t < 3) T[t] = trans[n*3 + t];
    __syncthreads();

    const float* src = (t < 48) ? (qpr + n*144 + t*3) : (kvpr + n*432 + (t-48)*3);
    float x = src[0], y = src[1], z = src[2];
    float wx = R[0]*x + R[1]*y + R[2]*z + T[0];
    float wy = R[3]*x + R[4]*y + R[5]*z + T[1];
    float wz = R[6]*x + R[7]*y + R[8]*z + T[2];
    if (t < 48) {
        float* d = qp + n*144 + t*3;
        d[0]=wx; d[1]=wy; d[2]=wz;
    } else {
        int pi = t - 48, h = pi/12, pp = pi%12;
        if (pp < 4) {
            float* d = kpT + (h*NN+n)*12 + pp*3;
            d[0]=wx; d[1]=wy; d[2]=wz;
        } else {
            int ch = h*40 + 16 + (pp-4)*3;
            vallT[(size_t)(ch+0)*NN + n] = wx;
            vallT[(size_t)(ch+1)*NN + n] = wy;
            vallT[(size_t)(ch+2)*NN + n] = wz;
        }
    }
}

// ---------------- Kernel C1: z-independent logits, ALL 12 heads per block ----------------
// Output layout lqd[i][j][h] (h-minor, 12 floats contiguous per (i,j)).
// grid (12 j-tiles of 64, 24 i-tiles of 32), block 256; per-h LDS staging.
__global__ __launch_bounds__(256) void kqk(
    const float* __restrict__ kT, const float* __restrict__ kpT,
    const float* __restrict__ q, const float* __restrict__ qp,
    const float* __restrict__ mask, const float* __restrict__ head_w,
    const float* __restrict__ bb, float* __restrict__ lqd)
{
    const int j0 = blockIdx.x * 64;
    const int i0 = blockIdx.y * 32;
    __shared__ float ktl[64][17], kpl[64][13];
    __shared__ float ql[32][17],  qpl[32][13];
    __shared__ float mi_l[32], mj_l[64];
    const int t = threadIdx.x;
    if (t < 32) mi_l[t] = mask[i0 + t];
    if (t < 64) mj_l[t] = mask[j0 + t];

    const int jl = t & 63, wv = t >> 6;

    for (int h = 0; h < 12; ++h) {
        __syncthreads();   // previous compute done, LDS reusable
        for (int idx = t; idx < 1024; idx += 256)
            ktl[idx >> 4][idx & 15] = kT[(size_t)(h*NN + j0 + (idx >> 4))*16 + (idx & 15)];
        for (int idx = t; idx < 768; idx += 256) {
            int r = idx / 12, e = idx - r*12;
            kpl[r][e] = kpT[(size_t)(h*NN + j0 + r)*12 + e];
        }
        for (int idx = t; idx < 512; idx += 256)
            ql[idx >> 4][idx & 15] = q[(i0 + (idx >> 4))*192 + h*16 + (idx & 15)];
        for (int idx = t; idx < 384; idx += 256) {
            int r = idx / 12, e = idx - r*12;
            qpl[r][e] = qp[(i0 + r)*144 + h*12 + e];
        }
        __syncthreads();

        const float hwh = log1pf(expf(head_w[h])) * SC_HW;
        const float bbh = bb[h] * SC_B;
        const float mj = mj_l[jl];
        #pragma unroll
        for (int k = 0; k < 8; ++k) {
            const int il = wv*8 + k;
            float qk = 0.f;
            #pragma unroll
            for (int c = 0; c < 16; ++c) qk = fmaf(ktl[jl][c], ql[il][c], qk);
            float d2 = 0.f;
            #pragma unroll
            for (int e = 0; e < 12; ++e) { float d = qpl[il][e] - kpl[jl][e]; d2 = fmaf(d, d, d2); }
            float mt = 1e9f * (mi_l[il]*mj - 1.0f);
            float lg = fmaf(qk, SC_QK, fmaf(-0.5f*hwh, d2, bbh)) + mt;
            lqd[((size_t)(i0+il)*NN + j0 + jl)*12 + h] = lg;
        }
    }
}

// ---------------- Kernel C2: g = lqd + SC_B*(z·Wb); row max. Pure streaming ----------------
// One block per row i; NO LDS staging, NO barriers in the loop. Wb in registers
// (lane = 8 channels x 12 heads); 16-lane butterfly reduce; group leader (cl==0)
// adds lqd, writes g[i][j][12], tracks max.
__global__ __launch_bounds__(256, 4) void kbias(
    const float* __restrict__ z, const float* __restrict__ Wb,
    const float* __restrict__ lqd, float* __restrict__ g_out,
    float* __restrict__ mrow)
{
    __shared__ float mxl[16][12];
    const int i = blockIdx.x, t = threadIdx.x;
    const int w = t >> 6, l = t & 63;
    const int grp = l >> 4, cl = l & 15;

    // Wb fragment: this lane's 8 channels for all 12 heads (24 float4 = 96 VGPR)
    float4 wva[12], wvb[12];
    #pragma unroll
    for (int h = 0; h < 12; ++h) {
        const float4* wp = (const float4*)(Wb + h*CZ + cl*8);
        wva[h] = wp[0];
        wvb[h] = wp[1];
    }

    float mx[12];
    #pragma unroll
    for (int h = 0; h < 12; ++h) mx[h] = -1e30f;

    for (int it = 0; it < 48; ++it) {
        const int j = it*16 + w*4 + grp;
        const float4* zr4 = (const float4*)(z + ((size_t)i*NN + j)*CZ) + cl*2;
        float4 za = zr4[0], zb = zr4[1];

        float b[12];
        #pragma unroll
        for (int h = 0; h < 12; ++h) {
            float acc;
            acc = za.x*wva[h].x;
            acc = fmaf(za.y, wva[h].y, acc);
            acc = fmaf(za.z, wva[h].z, acc);
            acc = fmaf(za.w, wva[h].w, acc);
            acc = fmaf(zb.x, wvb[h].x, acc);
            acc = fmaf(zb.y, wvb[h].y, acc);
            acc = fmaf(zb.z, wvb[h].z, acc);
            acc = fmaf(zb.w, wvb[h].w, acc);
            b[h] = acc;
        }
        #pragma unroll
        for (int h = 0; h < 12; ++h) {
            b[h] += __shfl_xor(b[h], 1, 16);
            b[h] += __shfl_xor(b[h], 2, 16);
            b[h] += __shfl_xor(b[h], 4, 16);
            b[h] += __shfl_xor(b[h], 8, 16);
        }
        if (cl == 0) {
            const float4* lq4 = (const float4*)(lqd + ((size_t)i*NN + j)*12);
            float4 qa = lq4[0], qb = lq4[1], qc = lq4[2];
            float g0  = fmaf(b[0],  SC_B, qa.x);
            float g1  = fmaf(b[1],  SC_B, qa.y);
            float g2  = fmaf(b[2],  SC_B, qa.z);
            float g3  = fmaf(b[3],  SC_B, qa.w);
            float g4  = fmaf(b[4],  SC_B, qb.x);
            float g5  = fmaf(b[5],  SC_B, qb.y);
            float g6  = fmaf(b[6],  SC_B, qb.z);
            float g7  = fmaf(b[7],  SC_B, qb.w);
            float g8  = fmaf(b[8],  SC_B, qc.x);
            float g9  = fmaf(b[9],  SC_B, qc.y);
            float g10 = fmaf(b[10], SC_B, qc.z);
            float g11 = fmaf(b[11], SC_B, qc.w);
            float4* go = (float4*)(g_out + ((size_t)i*NN + j)*12);
            float4 oa; oa.x = g0; oa.y = g1; oa.z = g2;  oa.w = g3;
            float4 ob; ob.x = g4; ob.y = g5; ob.z = g6;  ob.w = g7;
            float4 oc; oc.x = g8; oc.y = g9; oc.z = g10; oc.w = g11;
            go[0] = oa; go[1] = ob; go[2] = oc;
            mx[0] = fmaxf(mx[0], g0);  mx[1] = fmaxf(mx[1], g1);
            mx[2] = fmaxf(mx[2], g2);  mx[3] = fmaxf(mx[3], g3);
            mx[4] = fmaxf(mx[4], g4);  mx[5] = fmaxf(mx[5], g5);
            mx[6] = fmaxf(mx[6], g6);  mx[7] = fmaxf(mx[7], g7);
            mx[8] = fmaxf(mx[8], g8);  mx[9] = fmaxf(mx[9], g9);
            mx[10] = fmaxf(mx[10], g10); mx[11] = fmaxf(mx[11], g11);
        }
    }

    if (cl == 0) {
        #pragma unroll
        for (int h = 0; h < 12; ++h) mxl[w*4 + grp][h] = mx[h];
    }
    __syncthreads();
    if (t < 12) {
        float m = mxl[0][t];
        #pragma unroll
        for (int r = 1; r < 16; ++r) m = fmaxf(m, mxl[r][t]);
        mrow[t*NN + i] = m;
    }
}

// ---------------- Kernel C3: softmax staging + o_pair + o/o_pt ----------------
__global__ __launch_bounds__(256, 4) void kfin(
    const float* __restrict__ z, const float* __restrict__ vallT,
    const float* __restrict__ g, const float* __restrict__ mrow,
    const float* __restrict__ rot, const float* __restrict__ trans,
    float* __restrict__ cat)
{
    __shared__ float an_l[12][776];
    __shared__ float sred[12][4];
    __shared__ float sinv[12];
    __shared__ float m_lds[12];
    __shared__ float optl[12][24];
    __shared__ float R[9], T[3];
    const int i = blockIdx.x, t = threadIdx.x, w = t >> 6, l = t & 63;
    if (t < 9) R[t] = rot[i*9 + t];
    if (t < 3) T[t] = trans[i*3 + t];
    if (t >= 16 && t < 28) m_lds[t-16] = mrow[(t-16)*NN + i];
    __syncthreads();

    float m0 = m_lds[0], m1 = m_lds[1], m2 = m_lds[2],  m3 = m_lds[3];
    float m4 = m_lds[4], m5 = m_lds[5], m6 = m_lds[6],  m7 = m_lds[7];
    float m8 = m_lds[8], m9 = m_lds[9], m10 = m_lds[10], m11 = m_lds[11];

    // ---- stage p = exp(g - m): thread t handles j = t, t+256, t+512 ----
    float4 psA = {0,0,0,0}, psB = {0,0,0,0}, psC = {0,0,0,0};
    const float4* gr4 = (const float4*)(g + (size_t)i*NN*12);
    #pragma unroll
    for (int jj = 0; jj < 3; ++jj) {
        const int j = jj*256 + t;
        float4 ga = gr4[j*3 + 0];
        float4 gb = gr4[j*3 + 1];
        float4 gc = gr4[j*3 + 2];
        float p0  = __expf(ga.x - m0),  p1  = __expf(ga.y - m1);
        float p2  = __expf(ga.z - m2),  p3  = __expf(ga.w - m3);
        float p4  = __expf(gb.x - m4),  p5  = __expf(gb.y - m5);
        float p6  = __expf(gb.z - m6),  p7  = __expf(gb.w - m7);
        float p8  = __expf(gc.x - m8),  p9  = __expf(gc.y - m9);
        float p10 = __expf(gc.z - m10), p11 = __expf(gc.w - m11);
        an_l[0][j] = p0;  an_l[1][j] = p1;  an_l[2][j] = p2;  an_l[3][j] = p3;
        an_l[4][j] = p4;  an_l[5][j] = p5;  an_l[6][j] = p6;  an_l[7][j] = p7;
        an_l[8][j] = p8;  an_l[9][j] = p9;  an_l[10][j] = p10; an_l[11][j] = p11;
        psA.x += p0;  psA.y += p1;  psA.z += p2;  psA.w += p3;
        psB.x += p4;  psB.y += p5;  psB.z += p6;  psB.w += p7;
        psC.x += p8;  psC.y += p9;  psC.z += p10; psC.w += p11;
    }
    {
        float sums[12] = {psA.x, psA.y, psA.z, psA.w, psB.x, psB.y, psB.z, psB.w,
                          psC.x, psC.y, psC.z, psC.w};
        #pragma unroll
        for (int h = 0; h < 12; ++h) {
            float s = sums[h];
            #pragma unroll
            for (int off = 32; off >= 1; off >>= 1) s += __shfl_xor(s, off, 64);
            if (l == 0) sred[h][w] = s;
        }
    }
    __syncthreads();
    if (t < 12) sinv[t] = 1.0f / (sred[t][0] + sred[t][1] + sred[t][2] + sred[t][3]);
    __syncthreads();

    // ---- phase B: o_pair = p @ z. wave covers 8 j per iter (4 loads in flight) ----
    {
        const int h0 = w*3, jo = l >> 5, c4 = l & 31;
        const float4* __restrict__ zr = (const float4*)(z + (size_t)i*NN*CZ) + c4;
        float4 a0 = {0,0,0,0}, a1 = {0,0,0,0}, a2 = {0,0,0,0};
        for (int jb = 0; jb < 96; ++jb) {
            const int j0 = jb*8 + jo*4;
            float4 z0 = zr[(size_t)(j0+0)*32];
            float4 z1 = zr[(size_t)(j0+1)*32];
            float4 z2 = zr[(size_t)(j0+2)*32];
            float4 z3 = zr[(size_t)(j0+3)*32];
            float4 pA = *(const float4*)&an_l[h0+0][j0];
            float4 pB = *(const float4*)&an_l[h0+1][j0];
            float4 pC = *(const float4*)&an_l[h0+2][j0];
            a0.x = fmaf(pA.x, z0.x, a0.x); a0.y = fmaf(pA.x, z0.y, a0.y);
            a0.z = fmaf(pA.x, z0.z, a0.z); a0.w = fmaf(pA.x, z0.w, a0.w);
            a0.x = fmaf(pA.y, z1.x, a0.x); a0.y = fmaf(pA.y, z1.y, a0.y);
            a0.z = fmaf(pA.y, z1.z, a0.z); a0.w = fmaf(pA.y, z1.w, a0.w);
            a0.x = fmaf(pA.z, z2.x, a0.x); a0.y = fmaf(pA.z, z2.y, a0.y);
            a0.z = fmaf(pA.z, z2.z, a0.z); a0.w = fmaf(pA.z, z2.w, a0.w);
            a0.x = fmaf(pA.w, z3.x, a0.x); a0.y = fmaf(pA.w, z3.y, a0.y);
            a0.z = fmaf(pA.w, z3.z, a0.z); a0.w = fmaf(pA.w, z3.w, a0.w);

            a1.x = fmaf(pB.x, z0.x, a1.x); a1.y = fmaf(pB.x, z0.y, a1.y);
            a1.z = fmaf(pB.x, z0.z, a1.z); a1.w = fmaf(pB.x, z0.w, a1.w);
            a1.x = fmaf(pB.y, z1.x, a1.x); a1.y = fmaf(pB.y, z1.y, a1.y);
            a1.z = fmaf(pB.y, z1.z, a1.z); a1.w = fmaf(pB.y, z1.w, a1.w);
            a1.x = fmaf(pB.z, z2.x, a1.x); a1.y = fmaf(pB.z, z2.y, a1.y);
            a1.z = fmaf(pB.z, z2.z, a1.z); a1.w = fmaf(pB.z, z2.w, a1.w);
            a1.x = fmaf(pB.w, z3.x, a1.x); a1.y = fmaf(pB.w, z3.y, a1.y);
            a1.z = fmaf(pB.w, z3.z, a1.z); a1.w = fmaf(pB.w, z3.w, a1.w);

            a2.x = fmaf(pC.x, z0.x, a2.x); a2.y = fmaf(pC.x, z0.y, a2.y);
            a2.z = fmaf(pC.x, z0.z, a2.z); a2.w = fmaf(pC.x, z0.w, a2.w);
            a2.x = fmaf(pC.y, z1.x, a2.x); a2.y = fmaf(pC.y, z1.y, a2.y);
            a2.z = fmaf(pC.y, z1.z, a2.z); a2.w = fmaf(pC.y, z1.w, a2.w);
            a2.x = fmaf(pC.z, z2.x, a2.x); a2.y = fmaf(pC.z, z2.y, a2.y);
            a2.z = fmaf(pC.z, z2.z, a2.z); a2.w = fmaf(pC.z, z2.w, a2.w);
            a2.x = fmaf(pC.w, z3.x, a2.x); a2.y = fmaf(pC.w, z3.y, a2.y);
            a2.z = fmaf(pC.w, z3.z, a2.z); a2.w = fmaf(pC.w, z3.w, a2.w);
        }
        a0.x += __shfl_xor(a0.x, 32, 64); a0.y += __shfl_xor(a0.y, 32, 64);
        a0.z += __shfl_xor(a0.z, 32, 64); a0.w += __shfl_xor(a0.w, 32, 64);
        a1.x += __shfl_xor(a1.x, 32, 64); a1.y += __shfl_xor(a1.y, 32, 64);
        a1.z += __shfl_xor(a1.z, 32, 64); a1.w += __shfl_xor(a1.w, 32, 64);
        a2.x += __shfl_xor(a2.x, 32, 64); a2.y += __shfl_xor(a2.y, 32, 64);
        a2.z += __shfl_xor(a2.z, 32, 64); a2.w += __shfl_xor(a2.w, 32, 64);
        if (jo == 0) {
            float* crow = cat + (size_t)i*OUTIN + 576;
            float i0v = sinv[h0+0], i1v = sinv[h0+1], i2v = sinv[h0+2];
            float4 o0; o0.x = a0.x*i0v; o0.y = a0.y*i0v; o0.z = a0.z*i0v; o0.w = a0.w*i0v;
            float4 o1; o1.x = a1.x*i1v; o1.y = a1.y*i1v; o1.z = a1.z*i1v; o1.w = a1.w*i1v;
            float4 o2; o2.x = a2.x*i2v; o2.y = a2.y*i2v; o2.z = a2.z*i2v; o2.w = a2.w*i2v;
            *(float4*)(crow + (h0+0)*128 + c4*4) = o0;
            *(float4*)(crow + (h0+1)*128 + c4*4) = o1;
            *(float4*)(crow + (h0+2)*128 + c4*4) = o2;
        }
    }

    // ---- phase C: o / o_pt = p @ vallT (L2-resident), wave-per-channel ----
    float* crow = cat + (size_t)i*OUTIN;
    for (int cc = 0; cc < 120; ++cc) {
        const int ch = w*120 + cc;
        const int h = ch / 40, e = ch % 40;
        const float2* __restrict__ vr = (const float2*)(vallT + (size_t)ch*NN);
        const float2* __restrict__ pr = (const float2*)(&an_l[h][0]);
        float ax = 0.f, ay = 0.f;
        #pragma unroll
        for (int jc = 0; jc < 6; ++jc) {
            float2 v = vr[jc*64 + l];
            float2 p = pr[jc*64 + l];
            ax = fmaf(p.x, v.x, ax);
            ay = fmaf(p.y, v.y, ay);
        }
        float sv = ax + ay;
        #pragma unroll
        for (int off = 32; off >= 1; off >>= 1) sv += __shfl_xor(sv, off, 64);
        if (l == 0) {
            float val = sv * sinv[h];
            if (e < 16) crow[h*16 + e] = val;
            else        optl[h][e-16] = val;
        }
    }
    __syncthreads();
    if (t < 96) {
        int h = t >> 3, p = t & 7;
        float wx = optl[h][p*3+0] - T[0];
        float wy = optl[h][p*3+1] - T[1];
        float wz = optl[h][p*3+2] - T[2];
        crow[192 + 0*96 + h*8 + p] = R[0]*wx + R[3]*wy + R[6]*wz;
        crow[192 + 1*96 + h*8 + p] = R[1]*wx + R[4]*wy + R[7]*wz;
        crow[192 + 2*96 + h*8 + p] = R[2]*wx + R[5]*wy + R[8]*wz;
        crow[480 + h*8 + p] = sqrtf(fmaf(wx,wx,fmaf(wy,wy,wz*wz)) + 1e-8f);
    }
}

// ---------------- Kernel D1: out partial = cat-tile @ Wout-tile^T (split-K) ----------------
__global__ __launch_bounds__(256) void koutp(
    const float* __restrict__ cat, const float* __restrict__ Wout,
    float* __restrict__ ptmp)
{
    __shared__ float ct[32][36];
    __shared__ float wt[64][36];
    const int n0 = blockIdx.x * 32, o0 = blockIdx.y * 64;
    const int k0 = blockIdx.z * 352;
    const int t = threadIdx.x;
    const int tn = (t >> 4) * 2;
    const int to = t & 15;

    float a00=0,a01=0,a02=0,a03=0, a10=0,a11=0,a12=0,a13=0;

    for (int c = 0; c < 11; ++c) {
        __syncthreads();
        #pragma unroll
        for (int u = 0; u < 4; ++u) {
            int idx = u*256 + t, r = idx >> 5, cc = idx & 31;
            ct[r][cc] = cat[(size_t)(n0 + r)*OUTIN + k0 + c*32 + cc];
        }
        #pragma unroll
        for (int u = 0; u < 8; ++u) {
            int idx = u*256 + t, r = idx >> 5, cc = idx & 31;
            wt[r][cc] = Wout[(size_t)(o0 + r)*OUTIN + k0 + c*32 + cc];
        }
        __syncthreads();
        #pragma unroll
        for (int kk = 0; kk < 32; kk += 4) {
            float4 c0 = *(const float4*)&ct[tn][kk];
            float4 c1 = *(const float4*)&ct[tn+1][kk];
            float4 w0 = *(const float4*)&wt[to][kk];
            float4 w1 = *(const float4*)&wt[to+16][kk];
            float4 w2 = *(const float4*)&wt[to+32][kk];
            float4 w3 = *(const float4*)&wt[to+48][kk];
            a00 = fmaf(c0.x,w0.x,a00); a00 = fmaf(c0.y,w0.y,a00); a00 = fmaf(c0.z,w0.z,a00); a00 = fmaf(c0.w,w0.w,a00);
            a01 = fmaf(c0.x,w1.x,a01); a01 = fmaf(c0.y,w1.y,a01); a01 = fmaf(c0.z,w1.z,a01); a01 = fmaf(c0.w,w1.w,a01);
            a02 = fmaf(c0.x,w2.x,a02); a02 = fmaf(c0.y,w2.y,a02); a02 = fmaf(c0.z,w2.z,a02); a02 = fmaf(c0.w,w2.w,a02);
            a03 = fmaf(c0.x,w3.x,a03); a03 = fmaf(c0.y,w3.y,a03); a03 = fmaf(c0.z,w3.z,a03); a03 = fmaf(c0.w,w3.w,a03);
            a10 = fmaf(c1.x,w0.x,a10); a10 = fmaf(c1.y,w0.y,a10); a10 = fmaf(c1.z,w0.z,a10); a10 = fmaf(c1.w,w0.w,a10);
            a11 = fmaf(c1.x,w1.x,a11); a11 = fmaf(c1.y,w1.y,a11); a11 = fmaf(c1.z,w1.z,a11); a11 = fmaf(c1.w,w1.w,a11);
            a12 = fmaf(c1.x,w2.x,a12); a12 = fmaf(c1.y,w2.y,a12); a12 = fmaf(c1.z,w2.z,a12); a12 = fmaf(c1.w,w2.w,a12);
            a13 = fmaf(c1.x,w3.x,a13); a13 = fmaf(c1.y,w3.y,a13); a13 = fmaf(c1.z,w3.z,a13); a13 = fmaf(c1.w,w3.w,a13);
        }
    }
    float* pb = ptmp + (size_t)blockIdx.z * (NN*384);
    pb[(size_t)(n0+tn+0)*384 + o0+to+ 0] = a00;
    pb[(size_t)(n0+tn+0)*384 + o0+to+16] = a01;
    pb[(size_t)(n0+tn+0)*384 + o0+to+32] = a02;
    pb[(size_t)(n0+tn+0)*384 + o0+to+48] = a03;
    pb[(size_t)(n0+tn+1)*384 + o0+to+ 0] = a10;
    pb[(size_t)(n0+tn+1)*384 + o0+to+16] = a11;
    pb[(size_t)(n0+tn+1)*384 + o0+to+32] = a12;
    pb[(size_t)(n0+tn+1)*384 + o0+to+48] = a13;
}

// ---------------- Kernel D2: reduce split-K partials + bias ----------------
__global__ __launch_bounds__(256) void kred(
    const float* __restrict__ ptmp, const float* __restrict__ bout,
    float* __restrict__ out)
{
    int idx = blockIdx.x * 256 + threadIdx.x;
    int o = idx % 384;
    float v = bout[o];
    #pragma unroll
    for (int s = 0; s < 6; ++s) v += ptmp[(size_t)s*(NN*384) + idx];
    out[idx] = v;
}

extern "C" void kernel_launch(void* const* d_in, const int* in_sizes, int n_in,
                              void* d_out, int out_size, void* d_ws, size_t ws_size,
                              hipStream_t stream) {
    const float* s      = (const float*)d_in[0];
    const float* z      = (const float*)d_in[1];
    const float* rot    = (const float*)d_in[2];
    const float* trans  = (const float*)d_in[3];
    const float* mask   = (const float*)d_in[4];
    const float* Wq     = (const float*)d_in[5];
    const float* bq     = (const float*)d_in[6];
    const float* Wkv    = (const float*)d_in[7];
    const float* bkv    = (const float*)d_in[8];
    const float* Wqp    = (const float*)d_in[9];
    const float* bqp    = (const float*)d_in[10];
    const float* Wkvp   = (const float*)d_in[11];
    const float* bkvp   = (const float*)d_in[12];
    const float* Wb     = (const float*)d_in[13];
    const float* bb     = (const float*)d_in[14];
    const float* head_w = (const float*)d_in[15];
    const float* Wout   = (const float*)d_in[16];
    const float* bout   = (const float*)d_in[17];
    float* out = (float*)d_out;
    float* ws  = (float*)d_ws;

    float* q     = ws;              // 147456
    float* kT    = ws + 147456;     // 147456
    float* kpT   = ws + 294912;     // 110592
    float* vallT = ws + 405504;     // 368640
    float* qp    = ws + 774144;     // 110592
    float* qpr   = ws + 884736;     // 110592
    float* kvpr  = ws + 995328;     // 331776
    float* mrow  = ws + 1327104;    // 9216
    float* cat   = ws + 1336320;    // 1622016
    float* lqd   = ws + 2958336;    // 7077888  [i][j][12]
    float* gbuf  = ws + 10036224;   // 7077888  [i][j][12]
    float* ptmp  = ws + 17114112;   // 1769472

    kproj<<<dim3(96, 9), 256, 0, stream>>>(s, Wq, bq, Wkv, bkv, Wqp, bqp, Wkvp, bkvp,
                                           q, kT, vallT, qpr, kvpr);
    krot<<<dim3(768), 192, 0, stream>>>(rot, trans, qpr, kvpr, qp, kpT, vallT);
    kqk<<<dim3(12, 24), 256, 0, stream>>>(kT, kpT, q, qp, mask, head_w, bb, lqd);
    kbias<<<dim3(768), 256, 0, stream>>>(z, Wb, lqd, gbuf, mrow);
    kfin<<<dim3(768), 256, 0, stream>>>(z, vallT, gbuf, mrow, rot, trans, cat);
    koutp<<<dim3(24, 6, 6), 256, 0, stream>>>(cat, Wout, ptmp);
    kred<<<dim3(1152), 256, 0, stream>>>(ptmp, bout, out);
}

// Round 8
// 493.033 us; speedup vs baseline: 1.1942x; 1.1942x over previous
//
#include <hip/hip_runtime.h>
#include <math.h>

#define NN 768
#define CS 384
#define CZ 128
#define CH 16
#define HH 12
#define PQ 4
#define PV 8
#define OUTIN 2112

#define SC_QK 0.14433756729740643f   // sqrt(1/(3*16))
#define SC_B  0.57735026918962576f   // sqrt(1/3)
#define SC_HW 0.13608276348795434f   // sqrt(2/(27*4))

// ---------------- Kernel A: input projections (s @ W.T + b) ----------------
__global__ __launch_bounds__(256) void kproj(
    const float* __restrict__ s,
    const float* __restrict__ Wq,  const float* __restrict__ bq,
    const float* __restrict__ Wkv, const float* __restrict__ bkv,
    const float* __restrict__ Wqp, const float* __restrict__ bqp,
    const float* __restrict__ Wkvp,const float* __restrict__ bkvp,
    float* __restrict__ q, float* __restrict__ kT, float* __restrict__ vallT,
    float* __restrict__ qpr, float* __restrict__ kvpr)
{
    __shared__ float s_lds[8*384];
    int n0 = blockIdx.x * 8;
    int t = threadIdx.x;
    for (int idx = t; idx < 8*384; idx += 256)
        s_lds[idx] = s[(n0 + idx/384)*384 + (idx%384)];
    __syncthreads();

    int o = blockIdx.y * 128 + (t & 127);
    int ng = t >> 7;
    const float* wrow; float bias;
    if (o < 192)      { wrow = Wq   + o*384;       bias = bq[o]; }
    else if (o < 576) { wrow = Wkv  + (o-192)*384; bias = bkv[o-192]; }
    else if (o < 720) { wrow = Wqp  + (o-576)*384; bias = bqp[o-576]; }
    else              { wrow = Wkvp + (o-720)*384; bias = bkvp[o-720]; }

    float acc[4] = {bias, bias, bias, bias};
    const float4* wr4 = reinterpret_cast<const float4*>(wrow);
    for (int c4 = 0; c4 < 96; ++c4) {
        float4 w = wr4[c4];
        #pragma unroll
        for (int nn = 0; nn < 4; ++nn) {
            const float* sr = &s_lds[(ng*4+nn)*384 + c4*4];
            acc[nn] = fmaf(w.x, sr[0], acc[nn]);
            acc[nn] = fmaf(w.y, sr[1], acc[nn]);
            acc[nn] = fmaf(w.z, sr[2], acc[nn]);
            acc[nn] = fmaf(w.w, sr[3], acc[nn]);
        }
    }
    #pragma unroll
    for (int nn = 0; nn < 4; ++nn) {
        int n = n0 + ng*4 + nn;
        float v = acc[nn];
        if (o < 192)      q[n*192 + o] = v;
        else if (o < 576) {
            int oo = o - 192, h = oo >> 5, cc = oo & 31;
            if (cc < 16) kT[(h*NN + n)*16 + cc] = v;
            else         vallT[(size_t)(h*40 + (cc-16))*NN + n] = v;
        }
        else if (o < 720) qpr[n*144 + (o-576)] = v;
        else              kvpr[n*432 + (o-720)] = v;
    }
}

// ---------------- Kernel B: apply frames (rot, trans) to points ----------------
__global__ __launch_bounds__(192) void krot(
    const float* __restrict__ rot, const float* __restrict__ trans,
    const float* __restrict__ qpr, const float* __restrict__ kvpr,
    float* __restrict__ qp, float* __restrict__ kpT, float* __restrict__ vallT)
{
    int n = blockIdx.x;
    __shared__ float R[9], T[3];
    int t = threadIdx.x;
    if (t < 9) R[t] = rot[n*9 + t];
    if (t < 3) T[t] = trans[n*3 + t];
    __syncthreads();

    const float* src = (t < 48) ? (qpr + n*144 + t*3) : (kvpr + n*432 + (t-48)*3);
    float x = src[0], y = src[1], z = src[2];
    float wx = R[0]*x + R[1]*y + R[2]*z + T[0];
    float wy = R[3]*x + R[4]*y + R[5]*z + T[1];
    float wz = R[6]*x + R[7]*y + R[8]*z + T[2];
    if (t < 48) {
        float* d = qp + n*144 + t*3;
        d[0]=wx; d[1]=wy; d[2]=wz;
    } else {
        int pi = t - 48, h = pi/12, pp = pi%12;
        if (pp < 4) {
            float* d = kpT + (h*NN+n)*12 + pp*3;
            d[0]=wx; d[1]=wy; d[2]=wz;
        } else {
            int ch = h*40 + 16 + (pp-4)*3;
            vallT[(size_t)(ch+0)*NN + n] = wx;
            vallT[(size_t)(ch+1)*NN + n] = wy;
            vallT[(size_t)(ch+2)*NN + n] = wz;
        }
    }
}

// ---------------- Kernel C1: z-independent logits, ALL 12 heads per block ----------------
// Output layout lqd[i][j][h] (h-minor).
__global__ __launch_bounds__(256) void kqk(
    const float* __restrict__ kT, const float* __restrict__ kpT,
    const float* __restrict__ q, const float* __restrict__ qp,
    const float* __restrict__ mask, const float* __restrict__ head_w,
    const float* __restrict__ bb, float* __restrict__ lqd)
{
    const int j0 = blockIdx.x * 64;
    const int i0 = blockIdx.y * 32;
    __shared__ float ktl[64][17], kpl[64][13];
    __shared__ float ql[32][17],  qpl[32][13];
    __shared__ float mi_l[32], mj_l[64];
    const int t = threadIdx.x;
    if (t < 32) mi_l[t] = mask[i0 + t];
    if (t < 64) mj_l[t] = mask[j0 + t];

    const int jl = t & 63, wv = t >> 6;

    for (int h = 0; h < 12; ++h) {
        __syncthreads();
        for (int idx = t; idx < 1024; idx += 256)
            ktl[idx >> 4][idx & 15] = kT[(size_t)(h*NN + j0 + (idx >> 4))*16 + (idx & 15)];
        for (int idx = t; idx < 768; idx += 256) {
            int r = idx / 12, e = idx - r*12;
            kpl[r][e] = kpT[(size_t)(h*NN + j0 + r)*12 + e];
        }
        for (int idx = t; idx < 512; idx += 256)
            ql[idx >> 4][idx & 15] = q[(i0 + (idx >> 4))*192 + h*16 + (idx & 15)];
        for (int idx = t; idx < 384; idx += 256) {
            int r = idx / 12, e = idx - r*12;
            qpl[r][e] = qp[(i0 + r)*144 + h*12 + e];
        }
        __syncthreads();

        const float hwh = log1pf(expf(head_w[h])) * SC_HW;
        const float bbh = bb[h] * SC_B;
        const float mj = mj_l[jl];
        #pragma unroll
        for (int k = 0; k < 8; ++k) {
            const int il = wv*8 + k;
            float qk = 0.f;
            #pragma unroll
            for (int c = 0; c < 16; ++c) qk = fmaf(ktl[jl][c], ql[il][c], qk);
            float d2 = 0.f;
            #pragma unroll
            for (int e = 0; e < 12; ++e) { float d = qpl[il][e] - kpl[jl][e]; d2 = fmaf(d, d, d2); }
            float mt = 1e9f * (mi_l[il]*mj - 1.0f);
            float lg = fmaf(qk, SC_QK, fmaf(-0.5f*hwh, d2, bbh)) + mt;
            lqd[((size_t)(i0+il)*NN + j0 + jl)*12 + h] = lg;
        }
    }
}

// ---------------- Kernel C2: g = lqd + SC_B*(z·Wb), IN PLACE over lqd ----------------
// grid (768 rows, 2 column-halves). 16-lane group owns 6 heads (2 groups per j).
// Wb fragment = 12 float4 = 48 VGPR per lane. Explicit z prefetch 1 iter ahead.
__global__ __launch_bounds__(256, 5) void kbias(
    const float* __restrict__ z, const float* __restrict__ Wb,
    float* __restrict__ g_inout, float* __restrict__ mrow /* [2][12*NN] */)
{
    __shared__ float mxl[16][6];
    const int i = blockIdx.x, jh = blockIdx.y;
    const int t = threadIdx.x;
    const int gid = t >> 4, cl = t & 15;
    const int hhalf = gid & 1, h0 = hhalf*6;
    const int jofs = gid >> 1;      // 0..7

    float4 wva[6], wvb[6];
    #pragma unroll
    for (int h = 0; h < 6; ++h) {
        const float4* wp = (const float4*)(Wb + (h0+h)*CZ + cl*8);
        wva[h] = wp[0]; wvb[h] = wp[1];
    }

    float mx[6];
    #pragma unroll
    for (int h = 0; h < 6; ++h) mx[h] = -1e30f;

    const int jbase = jh*384;
    const float4* zq0 = (const float4*)(z + ((size_t)i*NN + jbase + jofs)*CZ) + cl*2;
    float4 za = zq0[0], zb = zq0[1];

    for (int it = 0; it < 48; ++it) {
        float4 zaN = za, zbN = zb;
        if (it + 1 < 48) {
            const int jn = jbase + (it+1)*8 + jofs;
            const float4* zq = (const float4*)(z + ((size_t)i*NN + jn)*CZ) + cl*2;
            zaN = zq[0]; zbN = zq[1];
        }
        const int j = jbase + it*8 + jofs;
        float b0, b1, b2, b3, b4, b5;
        #define BDOT(BV, H)                                        \
            BV = za.x*wva[H].x;                                    \
            BV = fmaf(za.y, wva[H].y, BV);                         \
            BV = fmaf(za.z, wva[H].z, BV);                         \
            BV = fmaf(za.w, wva[H].w, BV);                         \
            BV = fmaf(zb.x, wvb[H].x, BV);                         \
            BV = fmaf(zb.y, wvb[H].y, BV);                         \
            BV = fmaf(zb.z, wvb[H].z, BV);                         \
            BV = fmaf(zb.w, wvb[H].w, BV);
        BDOT(b0, 0) BDOT(b1, 1) BDOT(b2, 2) BDOT(b3, 3) BDOT(b4, 4) BDOT(b5, 5)
        #undef BDOT
        #define BRED(BV)                                           \
            BV += __shfl_xor(BV, 1, 16);                           \
            BV += __shfl_xor(BV, 2, 16);                           \
            BV += __shfl_xor(BV, 4, 16);                           \
            BV += __shfl_xor(BV, 8, 16);
        BRED(b0) BRED(b1) BRED(b2) BRED(b3) BRED(b4) BRED(b5)
        #undef BRED
        if (cl == 0) {
            float* gp = g_inout + ((size_t)i*NN + j)*12 + h0;
            float2 qa = *(const float2*)(gp + 0);
            float2 qb = *(const float2*)(gp + 2);
            float2 qc = *(const float2*)(gp + 4);
            float g0 = fmaf(b0, SC_B, qa.x);
            float g1 = fmaf(b1, SC_B, qa.y);
            float g2 = fmaf(b2, SC_B, qb.x);
            float g3 = fmaf(b3, SC_B, qb.y);
            float g4 = fmaf(b4, SC_B, qc.x);
            float g5 = fmaf(b5, SC_B, qc.y);
            float2 oa; oa.x = g0; oa.y = g1;
            float2 ob; ob.x = g2; ob.y = g3;
            float2 oc; oc.x = g4; oc.y = g5;
            *(float2*)(gp + 0) = oa;
            *(float2*)(gp + 2) = ob;
            *(float2*)(gp + 4) = oc;
            mx[0] = fmaxf(mx[0], g0); mx[1] = fmaxf(mx[1], g1);
            mx[2] = fmaxf(mx[2], g2); mx[3] = fmaxf(mx[3], g3);
            mx[4] = fmaxf(mx[4], g4); mx[5] = fmaxf(mx[5], g5);
        }
        za = zaN; zb = zbN;
    }

    if (cl == 0) {
        #pragma unroll
        for (int h = 0; h < 6; ++h) mxl[gid][h] = mx[h];
    }
    __syncthreads();
    if (t < 12) {
        const int hh = (t >= 6) ? 1 : 0, hl = t - hh*6;
        float m = -1e30f;
        #pragma unroll
        for (int gg = 0; gg < 8; ++gg) m = fmaxf(m, mxl[gg*2 + hh][hl]);
        mrow[jh*(12*NN) + t*NN + i] = m;
    }
}

// ---------------- Kernel C3: softmax staging + o_pair + o/o_pt ----------------
// grid (768 rows, 2 channel-halves). Both halves stage p; phase B covers this
// block's 64 z-channels; phase C (+epilogue) runs in jh==1 blocks only.
__global__ __launch_bounds__(256, 4) void kfin(
    const float* __restrict__ z, const float* __restrict__ vallT,
    const float* __restrict__ g, const float* __restrict__ mrow,
    const float* __restrict__ rot, const float* __restrict__ trans,
    float* __restrict__ cat)
{
    __shared__ float an_l[12][776];
    __shared__ float sred[12][4];
    __shared__ float sinv[12];
    __shared__ float m_lds[12];
    __shared__ float optl[12][24];
    __shared__ float R[9], T[3];
    const int i = blockIdx.x, jh = blockIdx.y;
    const int t = threadIdx.x, w = t >> 6, l = t & 63;
    if (t < 9) R[t] = rot[i*9 + t];
    if (t < 3) T[t] = trans[i*3 + t];
    if (t >= 16 && t < 28) {
        const int h = t - 16;
        m_lds[h] = fmaxf(mrow[h*NN + i], mrow[12*NN + h*NN + i]);
    }
    __syncthreads();

    float m0 = m_lds[0], m1 = m_lds[1], m2 = m_lds[2],  m3 = m_lds[3];
    float m4 = m_lds[4], m5 = m_lds[5], m6 = m_lds[6],  m7 = m_lds[7];
    float m8 = m_lds[8], m9 = m_lds[9], m10 = m_lds[10], m11 = m_lds[11];

    // ---- stage p = exp(g - m): thread t handles j = t, t+256, t+512 ----
    float4 psA = {0,0,0,0}, psB = {0,0,0,0}, psC = {0,0,0,0};
    const float4* gr4 = (const float4*)(g + (size_t)i*NN*12);
    #pragma unroll
    for (int jj = 0; jj < 3; ++jj) {
        const int j = jj*256 + t;
        float4 ga = gr4[j*3 + 0];
        float4 gb = gr4[j*3 + 1];
        float4 gc = gr4[j*3 + 2];
        float p0  = __expf(ga.x - m0),  p1  = __expf(ga.y - m1);
        float p2  = __expf(ga.z - m2),  p3  = __expf(ga.w - m3);
        float p4  = __expf(gb.x - m4),  p5  = __expf(gb.y - m5);
        float p6  = __expf(gb.z - m6),  p7  = __expf(gb.w - m7);
        float p8  = __expf(gc.x - m8),  p9  = __expf(gc.y - m9);
        float p10 = __expf(gc.z - m10), p11 = __expf(gc.w - m11);
        an_l[0][j] = p0;  an_l[1][j] = p1;  an_l[2][j] = p2;  an_l[3][j] = p3;
        an_l[4][j] = p4;  an_l[5][j] = p5;  an_l[6][j] = p6;  an_l[7][j] = p7;
        an_l[8][j] = p8;  an_l[9][j] = p9;  an_l[10][j] = p10; an_l[11][j] = p11;
        psA.x += p0;  psA.y += p1;  psA.z += p2;  psA.w += p3;
        psB.x += p4;  psB.y += p5;  psB.z += p6;  psB.w += p7;
        psC.x += p8;  psC.y += p9;  psC.z += p10; psC.w += p11;
    }
    {
        float sums[12] = {psA.x, psA.y, psA.z, psA.w, psB.x, psB.y, psB.z, psB.w,
                          psC.x, psC.y, psC.z, psC.w};
        #pragma unroll
        for (int h = 0; h < 12; ++h) {
            float s = sums[h];
            #pragma unroll
            for (int off = 32; off >= 1; off >>= 1) s += __shfl_xor(s, off, 64);
            if (l == 0) sred[h][w] = s;
        }
    }
    __syncthreads();
    if (t < 12) sinv[t] = 1.0f / (sred[t][0] + sred[t][1] + sred[t][2] + sred[t][3]);
    __syncthreads();

    // ---- phase B: o_pair over this block's 64 channels; wave covers 16 j/iter ----
    {
        const int h0 = w*3, jo = l >> 4, c4b = l & 15;
        const float4* __restrict__ zr = (const float4*)(z + (size_t)i*NN*CZ) + jh*16 + c4b;
        float4 a0 = {0,0,0,0}, a1 = {0,0,0,0}, a2 = {0,0,0,0};
        for (int jb = 0; jb < 48; ++jb) {
            const int j0 = jb*16 + jo*4;
            float4 z0 = zr[(size_t)(j0+0)*32];
            float4 z1 = zr[(size_t)(j0+1)*32];
            float4 z2 = zr[(size_t)(j0+2)*32];
            float4 z3 = zr[(size_t)(j0+3)*32];
            float4 pA = *(const float4*)&an_l[h0+0][j0];
            float4 pB = *(const float4*)&an_l[h0+1][j0];
            float4 pC = *(const float4*)&an_l[h0+2][j0];
            a0.x = fmaf(pA.x, z0.x, a0.x); a0.y = fmaf(pA.x, z0.y, a0.y);
            a0.z = fmaf(pA.x, z0.z, a0.z); a0.w = fmaf(pA.x, z0.w, a0.w);
            a0.x = fmaf(pA.y, z1.x, a0.x); a0.y = fmaf(pA.y, z1.y, a0.y);
            a0.z = fmaf(pA.y, z1.z, a0.z); a0.w = fmaf(pA.y, z1.w, a0.w);
            a0.x = fmaf(pA.z, z2.x, a0.x); a0.y = fmaf(pA.z, z2.y, a0.y);
            a0.z = fmaf(pA.z, z2.z, a0.z); a0.w = fmaf(pA.z, z2.w, a0.w);
            a0.x = fmaf(pA.w, z3.x, a0.x); a0.y = fmaf(pA.w, z3.y, a0.y);
            a0.z = fmaf(pA.w, z3.z, a0.z); a0.w = fmaf(pA.w, z3.w, a0.w);

            a1.x = fmaf(pB.x, z0.x, a1.x); a1.y = fmaf(pB.x, z0.y, a1.y);
            a1.z = fmaf(pB.x, z0.z, a1.z); a1.w = fmaf(pB.x, z0.w, a1.w);
            a1.x = fmaf(pB.y, z1.x, a1.x); a1.y = fmaf(pB.y, z1.y, a1.y);
            a1.z = fmaf(pB.y, z1.z, a1.z); a1.w = fmaf(pB.y, z1.w, a1.w);
            a1.x = fmaf(pB.z, z2.x, a1.x); a1.y = fmaf(pB.z, z2.y, a1.y);
            a1.z = fmaf(pB.z, z2.z, a1.z); a1.w = fmaf(pB.z, z2.w, a1.w);
            a1.x = fmaf(pB.w, z3.x, a1.x); a1.y = fmaf(pB.w, z3.y, a1.y);
            a1.z = fmaf(pB.w, z3.z, a1.z); a1.w = fmaf(pB.w, z3.w, a1.w);

            a2.x = fmaf(pC.x, z0.x, a2.x); a2.y = fmaf(pC.x, z0.y, a2.y);
            a2.z = fmaf(pC.x, z0.z, a2.z); a2.w = fmaf(pC.x, z0.w, a2.w);
            a2.x = fmaf(pC.y, z1.x, a2.x); a2.y = fmaf(pC.y, z1.y, a2.y);
            a2.z = fmaf(pC.y, z1.z, a2.z); a2.w = fmaf(pC.y, z1.w, a2.w);
            a2.x = fmaf(pC.z, z2.x, a2.x); a2.y = fmaf(pC.z, z2.y, a2.y);
            a2.z = fmaf(pC.z, z2.z, a2.z); a2.w = fmaf(pC.z, z2.w, a2.w);
            a2.x = fmaf(pC.w, z3.x, a2.x); a2.y = fmaf(pC.w, z3.y, a2.y);
            a2.z = fmaf(pC.w, z3.z, a2.z); a2.w = fmaf(pC.w, z3.w, a2.w);
        }
        #define FOLD(V)                                            \
            V.x += __shfl_xor(V.x, 16, 64); V.y += __shfl_xor(V.y, 16, 64); \
            V.z += __shfl_xor(V.z, 16, 64); V.w += __shfl_xor(V.w, 16, 64); \
            V.x += __shfl_xor(V.x, 32, 64); V.y += __shfl_xor(V.y, 32, 64); \
            V.z += __shfl_xor(V.z, 32, 64); V.w += __shfl_xor(V.w, 32, 64);
        FOLD(a0) FOLD(a1) FOLD(a2)
        #undef FOLD
        if (jo == 0) {
            float* crow = cat + (size_t)i*OUTIN + 576 + jh*64;
            float i0v = sinv[h0+0], i1v = sinv[h0+1], i2v = sinv[h0+2];
            float4 o0; o0.x = a0.x*i0v; o0.y = a0.y*i0v; o0.z = a0.z*i0v; o0.w = a0.w*i0v;
            float4 o1; o1.x = a1.x*i1v; o1.y = a1.y*i1v; o1.z = a1.z*i1v; o1.w = a1.w*i1v;
            float4 o2; o2.x = a2.x*i2v; o2.y = a2.y*i2v; o2.z = a2.z*i2v; o2.w = a2.w*i2v;
            *(float4*)(crow + (h0+0)*128 + c4b*4) = o0;
            *(float4*)(crow + (h0+1)*128 + c4b*4) = o1;
            *(float4*)(crow + (h0+2)*128 + c4b*4) = o2;
        }
    }

    if (jh == 0) return;

    // ---- phase C: o / o_pt = p @ vallT (L2-resident), wave-per-channel ----
    float* crow = cat + (size_t)i*OUTIN;
    for (int cc = 0; cc < 120; ++cc) {
        const int ch = w*120 + cc;
        const int h = ch / 40, e = ch % 40;
        const float2* __restrict__ vr = (const float2*)(vallT + (size_t)ch*NN);
        const float2* __restrict__ pr = (const float2*)(&an_l[h][0]);
        float ax = 0.f, ay = 0.f;
        #pragma unroll
        for (int jc = 0; jc < 6; ++jc) {
            float2 v = vr[jc*64 + l];
            float2 p = pr[jc*64 + l];
            ax = fmaf(p.x, v.x, ax);
            ay = fmaf(p.y, v.y, ay);
        }
        float sv = ax + ay;
        #pragma unroll
        for (int off = 32; off >= 1; off >>= 1) sv += __shfl_xor(sv, off, 64);
        if (l == 0) {
            float val = sv * sinv[h];
            if (e < 16) crow[h*16 + e] = val;
            else        optl[h][e-16] = val;
        }
    }
    __syncthreads();
    if (t < 96) {
        int h = t >> 3, p = t & 7;
        float wx = optl[h][p*3+0] - T[0];
        float wy = optl[h][p*3+1] - T[1];
        float wz = optl[h][p*3+2] - T[2];
        crow[192 + 0*96 + h*8 + p] = R[0]*wx + R[3]*wy + R[6]*wz;
        crow[192 + 1*96 + h*8 + p] = R[1]*wx + R[4]*wy + R[7]*wz;
        crow[192 + 2*96 + h*8 + p] = R[2]*wx + R[5]*wy + R[8]*wz;
        crow[480 + h*8 + p] = sqrtf(fmaf(wx,wx,fmaf(wy,wy,wz*wz)) + 1e-8f);
    }
}

// ---------------- Kernel D1: out partial = cat-tile @ Wout-tile^T (split-K) ----------------
__global__ __launch_bounds__(256) void koutp(
    const float* __restrict__ cat, const float* __restrict__ Wout,
    float* __restrict__ ptmp)
{
    __shared__ float ct[32][36];
    __shared__ float wt[64][36];
    const int n0 = blockIdx.x * 32, o0 = blockIdx.y * 64;
    const int k0 = blockIdx.z * 352;
    const int t = threadIdx.x;
    const int tn = (t >> 4) * 2;
    const int to = t & 15;

    float a00=0,a01=0,a02=0,a03=0, a10=0,a11=0,a12=0,a13=0;

    for (int c = 0; c < 11; ++c) {
        __syncthreads();
        #pragma unroll
        for (int u = 0; u < 4; ++u) {
            int idx = u*256 + t, r = idx >> 5, cc = idx & 31;
            ct[r][cc] = cat[(size_t)(n0 + r)*OUTIN + k0 + c*32 + cc];
        }
        #pragma unroll
        for (int u = 0; u < 8; ++u) {
            int idx = u*256 + t, r = idx >> 5, cc = idx & 31;
            wt[r][cc] = Wout[(size_t)(o0 + r)*OUTIN + k0 + c*32 + cc];
        }
        __syncthreads();
        #pragma unroll
        for (int kk = 0; kk < 32; kk += 4) {
            float4 c0 = *(const float4*)&ct[tn][kk];
            float4 c1 = *(const float4*)&ct[tn+1][kk];
            float4 w0 = *(const float4*)&wt[to][kk];
            float4 w1 = *(const float4*)&wt[to+16][kk];
            float4 w2 = *(const float4*)&wt[to+32][kk];
            float4 w3 = *(const float4*)&wt[to+48][kk];
            a00 = fmaf(c0.x,w0.x,a00); a00 = fmaf(c0.y,w0.y,a00); a00 = fmaf(c0.z,w0.z,a00); a00 = fmaf(c0.w,w0.w,a00);
            a01 = fmaf(c0.x,w1.x,a01); a01 = fmaf(c0.y,w1.y,a01); a01 = fmaf(c0.z,w1.z,a01); a01 = fmaf(c0.w,w1.w,a01);
            a02 = fmaf(c0.x,w2.x,a02); a02 = fmaf(c0.y,w2.y,a02); a02 = fmaf(c0.z,w2.z,a02); a02 = fmaf(c0.w,w2.w,a02);
            a03 = fmaf(c0.x,w3.x,a03); a03 = fmaf(c0.y,w3.y,a03); a03 = fmaf(c0.z,w3.z,a03); a03 = fmaf(c0.w,w3.w,a03);
            a10 = fmaf(c1.x,w0.x,a10); a10 = fmaf(c1.y,w0.y,a10); a10 = fmaf(c1.z,w0.z,a10); a10 = fmaf(c1.w,w0.w,a10);
            a11 = fmaf(c1.x,w1.x,a11); a11 = fmaf(c1.y,w1.y,a11); a11 = fmaf(c1.z,w1.z,a11); a11 = fmaf(c1.w,w1.w,a11);
            a12 = fmaf(c1.x,w2.x,a12); a12 = fmaf(c1.y,w2.y,a12); a12 = fmaf(c1.z,w2.z,a12); a12 = fmaf(c1.w,w2.w,a12);
            a13 = fmaf(c1.x,w3.x,a13); a13 = fmaf(c1.y,w3.y,a13); a13 = fmaf(c1.z,w3.z,a13); a13 = fmaf(c1.w,w3.w,a13);
        }
    }
    float* pb = ptmp + (size_t)blockIdx.z * (NN*384);
    pb[(size_t)(n0+tn+0)*384 + o0+to+ 0] = a00;
    pb[(size_t)(n0+tn+0)*384 + o0+to+16] = a01;
    pb[(size_t)(n0+tn+0)*384 + o0+to+32] = a02;
    pb[(size_t)(n0+tn+0)*384 + o0+to+48] = a03;
    pb[(size_t)(n0+tn+1)*384 + o0+to+ 0] = a10;
    pb[(size_t)(n0+tn+1)*384 + o0+to+16] = a11;
    pb[(size_t)(n0+tn+1)*384 + o0+to+32] = a12;
    pb[(size_t)(n0+tn+1)*384 + o0+to+48] = a13;
}

// ---------------- Kernel D2: reduce split-K partials + bias ----------------
__global__ __launch_bounds__(256) void kred(
    const float* __restrict__ ptmp, const float* __restrict__ bout,
    float* __restrict__ out)
{
    int idx = blockIdx.x * 256 + threadIdx.x;
    int o = idx % 384;
    float v = bout[o];
    #pragma unroll
    for (int s = 0; s < 6; ++s) v += ptmp[(size_t)s*(NN*384) + idx];
    out[idx] = v;
}

extern "C" void kernel_launch(void* const* d_in, const int* in_sizes, int n_in,
                              void* d_out, int out_size, void* d_ws, size_t ws_size,
                              hipStream_t stream) {
    const float* s      = (const float*)d_in[0];
    const float* z      = (const float*)d_in[1];
    const float* rot    = (const float*)d_in[2];
    const float* trans  = (const float*)d_in[3];
    const float* mask   = (const float*)d_in[4];
    const float* Wq     = (const float*)d_in[5];
    const float* bq     = (const float*)d_in[6];
    const float* Wkv    = (const float*)d_in[7];
    const float* bkv    = (const float*)d_in[8];
    const float* Wqp    = (const float*)d_in[9];
    const float* bqp    = (const float*)d_in[10];
    const float* Wkvp   = (const float*)d_in[11];
    const float* bkvp   = (const float*)d_in[12];
    const float* Wb     = (const float*)d_in[13];
    const float* bb     = (const float*)d_in[14];
    const float* head_w = (const float*)d_in[15];
    const float* Wout   = (const float*)d_in[16];
    const float* bout   = (const float*)d_in[17];
    float* out = (float*)d_out;
    float* ws  = (float*)d_ws;

    float* q     = ws;              // 147456
    float* kT    = ws + 147456;     // 147456
    float* kpT   = ws + 294912;     // 110592
    float* vallT = ws + 405504;     // 368640
    float* qp    = ws + 774144;     // 110592
    float* qpr   = ws + 884736;     // 110592
    float* kvpr  = ws + 995328;     // 331776
    float* mrow  = ws + 1327104;    // 2*12*768 = 18432
    float* cat   = ws + 1345536;    // 1622016
    float* lqd   = ws + 2967552;    // 7077888  [i][j][12]; g written in place
    float* ptmp  = ws + 10045440;   // 1769472

    kproj<<<dim3(96, 9), 256, 0, stream>>>(s, Wq, bq, Wkv, bkv, Wqp, bqp, Wkvp, bkvp,
                                           q, kT, vallT, qpr, kvpr);
    krot<<<dim3(768), 192, 0, stream>>>(rot, trans, qpr, kvpr, qp, kpT, vallT);
    kqk<<<dim3(12, 24), 256, 0, stream>>>(kT, kpT, q, qp, mask, head_w, bb, lqd);
    kbias<<<dim3(768, 2), 256, 0, stream>>>(z, Wb, lqd, mrow);
    kfin<<<dim3(768, 2), 256, 0, stream>>>(z, vallT, lqd, mrow, rot, trans, cat);
    koutp<<<dim3(24, 6, 6), 256, 0, stream>>>(cat, Wout, ptmp);
    kred<<<dim3(1152), 256, 0, stream>>>(ptmp, bout, out);
}

// Round 9
// 471.958 us; speedup vs baseline: 1.2476x; 1.0447x over previous
//
#include <hip/hip_runtime.h>
#include <math.h>

#define NN 768
#define CS 384
#define CZ 128
#define CH 16
#define HH 12
#define PQ 4
#define PV 8
#define OUTIN 2112

#define SC_QK 0.14433756729740643f   // sqrt(1/(3*16))
#define SC_B  0.57735026918962576f   // sqrt(1/3)
#define SC_HW 0.13608276348795434f   // sqrt(2/(27*4))
#define MSLACK 12.0f                 // safe-softmax headroom over lqd row max

// ---------------- Kernel A: input projections (s @ W.T + b) ----------------
__global__ __launch_bounds__(256) void kproj(
    const float* __restrict__ s,
    const float* __restrict__ Wq,  const float* __restrict__ bq,
    const float* __restrict__ Wkv, const float* __restrict__ bkv,
    const float* __restrict__ Wqp, const float* __restrict__ bqp,
    const float* __restrict__ Wkvp,const float* __restrict__ bkvp,
    float* __restrict__ q, float* __restrict__ kT, float* __restrict__ vallT,
    float* __restrict__ qpr, float* __restrict__ kvpr)
{
    __shared__ float s_lds[8*384];
    int n0 = blockIdx.x * 8;
    int t = threadIdx.x;
    for (int idx = t; idx < 8*384; idx += 256)
        s_lds[idx] = s[(n0 + idx/384)*384 + (idx%384)];
    __syncthreads();

    int o = blockIdx.y * 128 + (t & 127);
    int ng = t >> 7;
    const float* wrow; float bias;
    if (o < 192)      { wrow = Wq   + o*384;       bias = bq[o]; }
    else if (o < 576) { wrow = Wkv  + (o-192)*384; bias = bkv[o-192]; }
    else if (o < 720) { wrow = Wqp  + (o-576)*384; bias = bqp[o-576]; }
    else              { wrow = Wkvp + (o-720)*384; bias = bkvp[o-720]; }

    float acc[4] = {bias, bias, bias, bias};
    const float4* wr4 = reinterpret_cast<const float4*>(wrow);
    for (int c4 = 0; c4 < 96; ++c4) {
        float4 w = wr4[c4];
        #pragma unroll
        for (int nn = 0; nn < 4; ++nn) {
            const float* sr = &s_lds[(ng*4+nn)*384 + c4*4];
            acc[nn] = fmaf(w.x, sr[0], acc[nn]);
            acc[nn] = fmaf(w.y, sr[1], acc[nn]);
            acc[nn] = fmaf(w.z, sr[2], acc[nn]);
            acc[nn] = fmaf(w.w, sr[3], acc[nn]);
        }
    }
    #pragma unroll
    for (int nn = 0; nn < 4; ++nn) {
        int n = n0 + ng*4 + nn;
        float v = acc[nn];
        if (o < 192)      q[n*192 + o] = v;
        else if (o < 576) {
            int oo = o - 192, h = oo >> 5, cc = oo & 31;
            if (cc < 16) kT[(h*NN + n)*16 + cc] = v;
            else         vallT[(size_t)(h*40 + (cc-16))*NN + n] = v;
        }
        else if (o < 720) qpr[n*144 + (o-576)] = v;
        else              kvpr[n*432 + (o-720)] = v;
    }
}

// ---------------- Kernel B: apply frames (rot, trans) to points ----------------
__global__ __launch_bounds__(192) void krot(
    const float* __restrict__ rot, const float* __restrict__ trans,
    const float* __restrict__ qpr, const float* __restrict__ kvpr,
    float* __restrict__ qp, float* __restrict__ kpT, float* __restrict__ vallT)
{
    int n = blockIdx.x;
    __shared__ float R[9], T[3];
    int t = threadIdx.x;
    if (t < 9) R[t] = rot[n*9 + t];
    if (t < 3) T[t] = trans[n*3 + t];
    __syncthreads();

    const float* src = (t < 48) ? (qpr + n*144 + t*3) : (kvpr + n*432 + (t-48)*3);
    float x = src[0], y = src[1], z = src[2];
    float wx = R[0]*x + R[1]*y + R[2]*z + T[0];
    float wy = R[3]*x + R[4]*y + R[5]*z + T[1];
    float wz = R[6]*x + R[7]*y + R[8]*z + T[2];
    if (t < 48) {
        float* d = qp + n*144 + t*3;
        d[0]=wx; d[1]=wy; d[2]=wz;
    } else {
        int pi = t - 48, h = pi/12, pp = pi%12;
        if (pp < 4) {
            float* d = kpT + (h*NN+n)*12 + pp*3;
            d[0]=wx; d[1]=wy; d[2]=wz;
        } else {
            int ch = h*40 + 16 + (pp-4)*3;
            vallT[(size_t)(ch+0)*NN + n] = wx;
            vallT[(size_t)(ch+1)*NN + n] = wy;
            vallT[(size_t)(ch+2)*NN + n] = wz;
        }
    }
}

// ---------------- Kernel C1: z-independent logits + per-tile row max ----------------
// lqd[i][j][h] h-minor; mpart[h][i][jt] = max over this block's 64 j.
__global__ __launch_bounds__(256) void kqk(
    const float* __restrict__ kT, const float* __restrict__ kpT,
    const float* __restrict__ q, const float* __restrict__ qp,
    const float* __restrict__ mask, const float* __restrict__ head_w,
    const float* __restrict__ bb, float* __restrict__ lqd,
    float* __restrict__ mpart)
{
    const int j0 = blockIdx.x * 64;
    const int i0 = blockIdx.y * 32;
    __shared__ float ktl[64][17], kpl[64][13];
    __shared__ float ql[32][17],  qpl[32][13];
    __shared__ float mi_l[32], mj_l[64];
    __shared__ float mpl[32][12];
    const int t = threadIdx.x;
    if (t < 32) mi_l[t] = mask[i0 + t];
    if (t < 64) mj_l[t] = mask[j0 + t];

    const int jl = t & 63, wv = t >> 6;

    for (int h = 0; h < 12; ++h) {
        __syncthreads();
        for (int idx = t; idx < 1024; idx += 256)
            ktl[idx >> 4][idx & 15] = kT[(size_t)(h*NN + j0 + (idx >> 4))*16 + (idx & 15)];
        for (int idx = t; idx < 768; idx += 256) {
            int r = idx / 12, e = idx - r*12;
            kpl[r][e] = kpT[(size_t)(h*NN + j0 + r)*12 + e];
        }
        for (int idx = t; idx < 512; idx += 256)
            ql[idx >> 4][idx & 15] = q[(i0 + (idx >> 4))*192 + h*16 + (idx & 15)];
        for (int idx = t; idx < 384; idx += 256) {
            int r = idx / 12, e = idx - r*12;
            qpl[r][e] = qp[(i0 + r)*144 + h*12 + e];
        }
        __syncthreads();

        const float hwh = log1pf(expf(head_w[h])) * SC_HW;
        const float bbh = bb[h] * SC_B;
        const float mj = mj_l[jl];
        #pragma unroll
        for (int k = 0; k < 8; ++k) {
            const int il = wv*8 + k;
            float qk = 0.f;
            #pragma unroll
            for (int c = 0; c < 16; ++c) qk = fmaf(ktl[jl][c], ql[il][c], qk);
            float d2 = 0.f;
            #pragma unroll
            for (int e = 0; e < 12; ++e) { float d = qpl[il][e] - kpl[jl][e]; d2 = fmaf(d, d, d2); }
            float mt = 1e9f * (mi_l[il]*mj - 1.0f);
            float lg = fmaf(qk, SC_QK, fmaf(-0.5f*hwh, d2, bbh)) + mt;
            lqd[((size_t)(i0+il)*NN + j0 + jl)*12 + h] = lg;
            float m = lg;
            m = fmaxf(m, __shfl_xor(m, 1, 64));
            m = fmaxf(m, __shfl_xor(m, 2, 64));
            m = fmaxf(m, __shfl_xor(m, 4, 64));
            m = fmaxf(m, __shfl_xor(m, 8, 64));
            m = fmaxf(m, __shfl_xor(m, 16, 64));
            m = fmaxf(m, __shfl_xor(m, 32, 64));
            if (jl == 0) mpl[il][h] = m;
        }
    }
    __syncthreads();
    if (t < 384) {
        int il = t / 12, h = t - il*12;
        mpart[((size_t)h*NN + i0 + il)*12 + blockIdx.x] = mpl[il][h];
    }
}

// ---------------- Kernel C2: p = exp(lqd + SC_B*(z·Wb) - M) IN PLACE; seg sums ----------------
// grid (768 i, 3 jseg). Thread t owns j = jseg*256+t: full 128-ch dot for 12 heads.
// Wb accesses are wave-uniform (scalar loads); no cross-lane reduce in hot loop.
__global__ __launch_bounds__(256, 6) void kpexp(
    const float* __restrict__ z, const float* __restrict__ Wb,
    const float* __restrict__ mpart, float* __restrict__ p_io,
    float* __restrict__ ssum)
{
    __shared__ float M_lds[12];
    __shared__ float sred[4][12];
    const int i = blockIdx.x, jseg = blockIdx.y;
    const int t = threadIdx.x, w = t >> 6, l = t & 63;
    if (t < 12) {
        const float4* mp = (const float4*)(mpart + ((size_t)t*NN + i)*12);
        float4 a = mp[0], b = mp[1], c = mp[2];
        float m = fmaxf(fmaxf(fmaxf(a.x,a.y), fmaxf(a.z,a.w)),
                 fmaxf(fmaxf(fmaxf(b.x,b.y), fmaxf(b.z,b.w)),
                       fmaxf(fmaxf(c.x,c.y), fmaxf(c.z,c.w))));
        M_lds[t] = m + MSLACK;
    }
    __syncthreads();

    const int j = jseg*256 + t;
    const float4* __restrict__ zr4 = (const float4*)(z + ((size_t)i*NN + j)*CZ);
    const float4* __restrict__ wb4 = (const float4*)Wb;   // uniform -> s_load

    float b0=0,b1=0,b2=0,b3=0,b4=0,b5=0,b6=0,b7=0,b8=0,b9=0,b10=0,b11=0;
    #define HD(B, H) { float4 wv = wb4[(H)*32 + c4]; \
        B = fmaf(zv.x, wv.x, B); B = fmaf(zv.y, wv.y, B); \
        B = fmaf(zv.z, wv.z, B); B = fmaf(zv.w, wv.w, B); }
    #pragma unroll 4
    for (int c4 = 0; c4 < 32; ++c4) {
        float4 zv = zr4[c4];
        HD(b0,0) HD(b1,1) HD(b2,2)  HD(b3,3)  HD(b4,4)   HD(b5,5)
        HD(b6,6) HD(b7,7) HD(b8,8)  HD(b9,9)  HD(b10,10) HD(b11,11)
    }
    #undef HD

    float* gp = p_io + ((size_t)i*NN + j)*12;
    float4 qa = *(const float4*)(gp + 0);
    float4 qb = *(const float4*)(gp + 4);
    float4 qc = *(const float4*)(gp + 8);
    float p0  = __expf(fmaf(b0,  SC_B, qa.x) - M_lds[0]);
    float p1  = __expf(fmaf(b1,  SC_B, qa.y) - M_lds[1]);
    float p2  = __expf(fmaf(b2,  SC_B, qa.z) - M_lds[2]);
    float p3  = __expf(fmaf(b3,  SC_B, qa.w) - M_lds[3]);
    float p4  = __expf(fmaf(b4,  SC_B, qb.x) - M_lds[4]);
    float p5  = __expf(fmaf(b5,  SC_B, qb.y) - M_lds[5]);
    float p6  = __expf(fmaf(b6,  SC_B, qb.z) - M_lds[6]);
    float p7  = __expf(fmaf(b7,  SC_B, qb.w) - M_lds[7]);
    float p8  = __expf(fmaf(b8,  SC_B, qc.x) - M_lds[8]);
    float p9  = __expf(fmaf(b9,  SC_B, qc.y) - M_lds[9]);
    float p10 = __expf(fmaf(b10, SC_B, qc.z) - M_lds[10]);
    float p11 = __expf(fmaf(b11, SC_B, qc.w) - M_lds[11]);
    float4 oa; oa.x = p0; oa.y = p1;  oa.z = p2;  oa.w = p3;
    float4 ob; ob.x = p4; ob.y = p5;  ob.z = p6;  ob.w = p7;
    float4 oc; oc.x = p8; oc.y = p9;  oc.z = p10; oc.w = p11;
    *(float4*)(gp + 0) = oa;
    *(float4*)(gp + 4) = ob;
    *(float4*)(gp + 8) = oc;

    #define RED(P) { P += __shfl_xor(P, 1, 64);  P += __shfl_xor(P, 2, 64); \
                     P += __shfl_xor(P, 4, 64);  P += __shfl_xor(P, 8, 64); \
                     P += __shfl_xor(P, 16, 64); P += __shfl_xor(P, 32, 64); }
    RED(p0) RED(p1) RED(p2) RED(p3) RED(p4)  RED(p5)
    RED(p6) RED(p7) RED(p8) RED(p9) RED(p10) RED(p11)
    #undef RED
    if (l == 0) {
        sred[w][0] = p0; sred[w][1] = p1; sred[w][2]  = p2;  sred[w][3]  = p3;
        sred[w][4] = p4; sred[w][5] = p5; sred[w][6]  = p6;  sred[w][7]  = p7;
        sred[w][8] = p8; sred[w][9] = p9; sred[w][10] = p10; sred[w][11] = p11;
    }
    __syncthreads();
    if (t < 12)
        ssum[(size_t)jseg*(12*NN) + t*NN + i] =
            sred[0][t] + sred[1][t] + sred[2][t] + sred[3][t];
}

// ---------------- Kernel C3: stage p + o_pair + o/o_pt ----------------
// grid (768, 2 ch-halves). Phase B: wave = (6 heads) x (j half) -> z loaded 2x/block.
__global__ __launch_bounds__(256, 3) void kfin(
    const float* __restrict__ z, const float* __restrict__ vallT,
    const float* __restrict__ p, const float* __restrict__ ssum,
    const float* __restrict__ rot, const float* __restrict__ trans,
    float* __restrict__ cat)
{
    __shared__ float an_l[12][776];
    __shared__ float4 psum[2][12][16];
    __shared__ float sinv[12];
    __shared__ float optl[12][24];
    __shared__ float R[9], T[3];
    const int i = blockIdx.x, jh = blockIdx.y;
    const int t = threadIdx.x, w = t >> 6, l = t & 63;
    if (t < 9) R[t] = rot[i*9 + t];
    if (t < 3) T[t] = trans[i*3 + t];
    if (t >= 16 && t < 28) {
        const int h = t - 16;
        sinv[h] = 1.0f / (ssum[h*NN + i] + ssum[12*NN + h*NN + i] + ssum[24*NN + h*NN + i]);
    }

    // ---- stage p (no exp needed) ----
    const float4* pr4 = (const float4*)(p + (size_t)i*NN*12);
    #pragma unroll
    for (int jj = 0; jj < 3; ++jj) {
        const int j = jj*256 + t;
        float4 ga = pr4[j*3 + 0];
        float4 gb = pr4[j*3 + 1];
        float4 gc = pr4[j*3 + 2];
        an_l[0][j] = ga.x;  an_l[1][j] = ga.y;  an_l[2][j]  = ga.z;  an_l[3][j]  = ga.w;
        an_l[4][j] = gb.x;  an_l[5][j] = gb.y;  an_l[6][j]  = gb.z;  an_l[7][j]  = gb.w;
        an_l[8][j] = gc.x;  an_l[9][j] = gc.y;  an_l[10][j] = gc.z;  an_l[11][j] = gc.w;
    }
    __syncthreads();

    // ---- phase B: wave (hgrp, jseg); lane (jo = l>>4, c4b = l&15) ----
    {
        const int hgrp = w & 1, jseg = w >> 1;
        const int h0 = hgrp*6;
        const int jo = l >> 4, c4b = l & 15;
        const float4* __restrict__ zr = (const float4*)(z + (size_t)i*NN*CZ) + jh*16 + c4b;
        float4 a0 = {0,0,0,0}, a1 = {0,0,0,0}, a2 = {0,0,0,0};
        float4 a3 = {0,0,0,0}, a4 = {0,0,0,0}, a5 = {0,0,0,0};
        for (int jb = 0; jb < 24; ++jb) {
            const int j0 = jseg*384 + jb*16 + jo*4;
            float4 z0 = zr[(size_t)(j0+0)*32];
            float4 z1 = zr[(size_t)(j0+1)*32];
            float4 z2 = zr[(size_t)(j0+2)*32];
            float4 z3 = zr[(size_t)(j0+3)*32];
            #define PBH(A, HH) { \
                float4 pv = *(const float4*)&an_l[h0+(HH)][j0]; \
                A.x = fmaf(pv.x, z0.x, A.x); A.y = fmaf(pv.x, z0.y, A.y); \
                A.z = fmaf(pv.x, z0.z, A.z); A.w = fmaf(pv.x, z0.w, A.w); \
                A.x = fmaf(pv.y, z1.x, A.x); A.y = fmaf(pv.y, z1.y, A.y); \
                A.z = fmaf(pv.y, z1.z, A.z); A.w = fmaf(pv.y, z1.w, A.w); \
                A.x = fmaf(pv.z, z2.x, A.x); A.y = fmaf(pv.z, z2.y, A.y); \
                A.z = fmaf(pv.z, z2.z, A.z); A.w = fmaf(pv.z, z2.w, A.w); \
                A.x = fmaf(pv.w, z3.x, A.x); A.y = fmaf(pv.w, z3.y, A.y); \
                A.z = fmaf(pv.w, z3.z, A.z); A.w = fmaf(pv.w, z3.w, A.w); }
            PBH(a0,0) PBH(a1,1) PBH(a2,2) PBH(a3,3) PBH(a4,4) PBH(a5,5)
            #undef PBH
        }
        // fold the 4 jo groups
        #define FOLD(V) \
            V.x += __shfl_xor(V.x, 16, 64); V.y += __shfl_xor(V.y, 16, 64); \
            V.z += __shfl_xor(V.z, 16, 64); V.w += __shfl_xor(V.w, 16, 64); \
            V.x += __shfl_xor(V.x, 32, 64); V.y += __shfl_xor(V.y, 32, 64); \
            V.z += __shfl_xor(V.z, 32, 64); V.w += __shfl_xor(V.w, 32, 64);
        FOLD(a0) FOLD(a1) FOLD(a2) FOLD(a3) FOLD(a4) FOLD(a5)
        #undef FOLD
        if (l < 16) {
            psum[jseg][h0+0][c4b] = a0;
            psum[jseg][h0+1][c4b] = a1;
            psum[jseg][h0+2][c4b] = a2;
            psum[jseg][h0+3][c4b] = a3;
            psum[jseg][h0+4][c4b] = a4;
            psum[jseg][h0+5][c4b] = a5;
        }
    }
    __syncthreads();
    if (t < 192) {
        const int hh = t >> 4, cc = t & 15;
        float4 v0 = psum[0][hh][cc], v1 = psum[1][hh][cc];
        const float sc = sinv[hh];
        float4 o;
        o.x = (v0.x + v1.x) * sc;
        o.y = (v0.y + v1.y) * sc;
        o.z = (v0.z + v1.z) * sc;
        o.w = (v0.w + v1.w) * sc;
        *(float4*)(cat + (size_t)i*OUTIN + 576 + hh*128 + jh*64 + cc*4) = o;
    }

    if (jh == 0) return;

    // ---- phase C: o / o_pt = p @ vallT (L2-resident), wave-per-channel ----
    float* crow = cat + (size_t)i*OUTIN;
    for (int cc = 0; cc < 120; ++cc) {
        const int ch = w*120 + cc;
        const int h = ch / 40, e = ch % 40;
        const float2* __restrict__ vr = (const float2*)(vallT + (size_t)ch*NN);
        const float2* __restrict__ pr = (const float2*)(&an_l[h][0]);
        float ax = 0.f, ay = 0.f;
        #pragma unroll
        for (int jc = 0; jc < 6; ++jc) {
            float2 v = vr[jc*64 + l];
            float2 pp = pr[jc*64 + l];
            ax = fmaf(pp.x, v.x, ax);
            ay = fmaf(pp.y, v.y, ay);
        }
        float sv = ax + ay;
        #pragma unroll
        for (int off = 32; off >= 1; off >>= 1) sv += __shfl_xor(sv, off, 64);
        if (l == 0) {
            float val = sv * sinv[h];
            if (e < 16) crow[h*16 + e] = val;
            else        optl[h][e-16] = val;
        }
    }
    __syncthreads();
    if (t < 96) {
        int h = t >> 3, pp = t & 7;
        float wx = optl[h][pp*3+0] - T[0];
        float wy = optl[h][pp*3+1] - T[1];
        float wz = optl[h][pp*3+2] - T[2];
        crow[192 + 0*96 + h*8 + pp] = R[0]*wx + R[3]*wy + R[6]*wz;
        crow[192 + 1*96 + h*8 + pp] = R[1]*wx + R[4]*wy + R[7]*wz;
        crow[192 + 2*96 + h*8 + pp] = R[2]*wx + R[5]*wy + R[8]*wz;
        crow[480 + h*8 + pp] = sqrtf(fmaf(wx,wx,fmaf(wy,wy,wz*wz)) + 1e-8f);
    }
}

// ---------------- Kernel D1: out partial = cat-tile @ Wout-tile^T (split-K) ----------------
__global__ __launch_bounds__(256) void koutp(
    const float* __restrict__ cat, const float* __restrict__ Wout,
    float* __restrict__ ptmp)
{
    __shared__ float ct[32][36];
    __shared__ float wt[64][36];
    const int n0 = blockIdx.x * 32, o0 = blockIdx.y * 64;
    const int k0 = blockIdx.z * 352;
    const int t = threadIdx.x;
    const int tn = (t >> 4) * 2;
    const int to = t & 15;

    float a00=0,a01=0,a02=0,a03=0, a10=0,a11=0,a12=0,a13=0;

    for (int c = 0; c < 11; ++c) {
        __syncthreads();
        #pragma unroll
        for (int u = 0; u < 4; ++u) {
            int idx = u*256 + t, r = idx >> 5, cc = idx & 31;
            ct[r][cc] = cat[(size_t)(n0 + r)*OUTIN + k0 + c*32 + cc];
        }
        #pragma unroll
        for (int u = 0; u < 8; ++u) {
            int idx = u*256 + t, r = idx >> 5, cc = idx & 31;
            wt[r][cc] = Wout[(size_t)(o0 + r)*OUTIN + k0 + c*32 + cc];
        }
        __syncthreads();
        #pragma unroll
        for (int kk = 0; kk < 32; kk += 4) {
            float4 c0 = *(const float4*)&ct[tn][kk];
            float4 c1 = *(const float4*)&ct[tn+1][kk];
            float4 w0 = *(const float4*)&wt[to][kk];
            float4 w1 = *(const float4*)&wt[to+16][kk];
            float4 w2 = *(const float4*)&wt[to+32][kk];
            float4 w3 = *(const float4*)&wt[to+48][kk];
            a00 = fmaf(c0.x,w0.x,a00); a00 = fmaf(c0.y,w0.y,a00); a00 = fmaf(c0.z,w0.z,a00); a00 = fmaf(c0.w,w0.w,a00);
            a01 = fmaf(c0.x,w1.x,a01); a01 = fmaf(c0.y,w1.y,a01); a01 = fmaf(c0.z,w1.z,a01); a01 = fmaf(c0.w,w1.w,a01);
            a02 = fmaf(c0.x,w2.x,a02); a02 = fmaf(c0.y,w2.y,a02); a02 = fmaf(c0.z,w2.z,a02); a02 = fmaf(c0.w,w2.w,a02);
            a03 = fmaf(c0.x,w3.x,a03); a03 = fmaf(c0.y,w3.y,a03); a03 = fmaf(c0.z,w3.z,a03); a03 = fmaf(c0.w,w3.w,a03);
            a10 = fmaf(c1.x,w0.x,a10); a10 = fmaf(c1.y,w0.y,a10); a10 = fmaf(c1.z,w0.z,a10); a10 = fmaf(c1.w,w0.w,a10);
            a11 = fmaf(c1.x,w1.x,a11); a11 = fmaf(c1.y,w1.y,a11); a11 = fmaf(c1.z,w1.z,a11); a11 = fmaf(c1.w,w1.w,a11);
            a12 = fmaf(c1.x,w2.x,a12); a12 = fmaf(c1.y,w2.y,a12); a12 = fmaf(c1.z,w2.z,a12); a12 = fmaf(c1.w,w2.w,a12);
            a13 = fmaf(c1.x,w3.x,a13); a13 = fmaf(c1.y,w3.y,a13); a13 = fmaf(c1.z,w3.z,a13); a13 = fmaf(c1.w,w3.w,a13);
        }
    }
    float* pb = ptmp + (size_t)blockIdx.z * (NN*384);
    pb[(size_t)(n0+tn+0)*384 + o0+to+ 0] = a00;
    pb[(size_t)(n0+tn+0)*384 + o0+to+16] = a01;
    pb[(size_t)(n0+tn+0)*384 + o0+to+32] = a02;
    pb[(size_t)(n0+tn+0)*384 + o0+to+48] = a03;
    pb[(size_t)(n0+tn+1)*384 + o0+to+ 0] = a10;
    pb[(size_t)(n0+tn+1)*384 + o0+to+16] = a11;
    pb[(size_t)(n0+tn+1)*384 + o0+to+32] = a12;
    pb[(size_t)(n0+tn+1)*384 + o0+to+48] = a13;
}

// ---------------- Kernel D2: reduce split-K partials + bias ----------------
__global__ __launch_bounds__(256) void kred(
    const float* __restrict__ ptmp, const float* __restrict__ bout,
    float* __restrict__ out)
{
    int idx = blockIdx.x * 256 + threadIdx.x;
    int o = idx % 384;
    float v = bout[o];
    #pragma unroll
    for (int s = 0; s < 6; ++s) v += ptmp[(size_t)s*(NN*384) + idx];
    out[idx] = v;
}

extern "C" void kernel_launch(void* const* d_in, const int* in_sizes, int n_in,
                              void* d_out, int out_size, void* d_ws, size_t ws_size,
                              hipStream_t stream) {
    const float* s      = (const float*)d_in[0];
    const float* z      = (const float*)d_in[1];
    const float* rot    = (const float*)d_in[2];
    const float* trans  = (const float*)d_in[3];
    const float* mask   = (const float*)d_in[4];
    const float* Wq     = (const float*)d_in[5];
    const float* bq     = (const float*)d_in[6];
    const float* Wkv    = (const float*)d_in[7];
    const float* bkv    = (const float*)d_in[8];
    const float* Wqp    = (const float*)d_in[9];
    const float* bqp    = (const float*)d_in[10];
    const float* Wkvp   = (const float*)d_in[11];
    const float* bkvp   = (const float*)d_in[12];
    const float* Wb     = (const float*)d_in[13];
    const float* bb     = (const float*)d_in[14];
    const float* head_w = (const float*)d_in[15];
    const float* Wout   = (const float*)d_in[16];
    const float* bout   = (const float*)d_in[17];
    float* out = (float*)d_out;
    float* ws  = (float*)d_ws;

    float* q     = ws;              // 147456
    float* kT    = ws + 147456;     // 147456
    float* kpT   = ws + 294912;     // 110592
    float* vallT = ws + 405504;     // 368640
    float* qp    = ws + 774144;     // 110592
    float* qpr   = ws + 884736;     // 110592
    float* kvpr  = ws + 995328;     // 331776
    float* mpart = ws + 1327104;    // 12*768*12 = 110592
    float* ssum  = ws + 1437696;    // 3*12*768 = 27648
    float* cat   = ws + 1465344;    // 1622016
    float* lqd   = ws + 3087360;    // 7077888 [i][j][12]; p written in place
    float* ptmp  = ws + 10165248;   // 1769472

    kproj<<<dim3(96, 9), 256, 0, stream>>>(s, Wq, bq, Wkv, bkv, Wqp, bqp, Wkvp, bkvp,
                                           q, kT, vallT, qpr, kvpr);
    krot<<<dim3(768), 192, 0, stream>>>(rot, trans, qpr, kvpr, qp, kpT, vallT);
    kqk<<<dim3(12, 24), 256, 0, stream>>>(kT, kpT, q, qp, mask, head_w, bb, lqd, mpart);
    kpexp<<<dim3(768, 3), 256, 0, stream>>>(z, Wb, mpart, lqd, ssum);
    kfin<<<dim3(768, 2), 256, 0, stream>>>(z, vallT, lqd, ssum, rot, trans, cat);
    koutp<<<dim3(24, 6, 6), 256, 0, stream>>>(cat, Wout, ptmp);
    kred<<<dim3(1152), 256, 0, stream>>>(ptmp, bout, out);
}